// Round 10
// baseline (261.785 us; speedup 1.0000x reference)
//
#include <hip/hip_runtime.h>

// Problem constants: B=2, S=2048, D=1024, H=16, DK=64
#define S_LEN 2048
#define DMODEL 1024
#define DHEAD 64

typedef _Float16 half8 __attribute__((ext_vector_type(8)));
typedef _Float16 half4 __attribute__((ext_vector_type(4)));
typedef float f32x4 __attribute__((ext_vector_type(4)));
typedef int i32x4 __attribute__((ext_vector_type(4)));

#define LOG2E 1.4426950408889634f

// async global->LDS, 16B per lane; LDS dest is wave-uniform base, HW writes lane i at base+16*i.
__device__ __forceinline__ void async_copy16(const void* g, void* l) {
  __builtin_amdgcn_global_load_lds((__attribute__((address_space(1))) const void*)g,
                                   (__attribute__((address_space(3))) void*)l,
                                   16, 0, 0);
}

#define WAIT_VMCNT(N) asm volatile("s_waitcnt vmcnt(" #N ")" ::: "memory")
#define WAIT_LGKM0() asm volatile("s_waitcnt lgkmcnt(0)" ::: "memory")
#define RAW_BARRIER() asm volatile("s_barrier" ::: "memory")

// ---------------- convert wq,wk,wv fp32 -> fp16 ----------------
__global__ __launch_bounds__(256) void convert_w(const float* __restrict__ wq,
                                                 const float* __restrict__ wk,
                                                 const float* __restrict__ wv,
                                                 _Float16* __restrict__ dst) {
  const float* src = (blockIdx.y == 0) ? wq : (blockIdx.y == 1) ? wk : wv;
  _Float16* d = dst + (size_t)blockIdx.y * (DMODEL * DMODEL);
  int i = (blockIdx.x * 256 + threadIdx.x) * 4;
  float4 v = *(const float4*)(src + i);
  half4 h;
  h[0] = (_Float16)v.x; h[1] = (_Float16)v.y;
  h[2] = (_Float16)v.z; h[3] = (_Float16)v.w;
  *(half4*)(d + i) = h;
}

// ---------------- convert wo fp32 -> fp16 (runs after attn; vt slot is dead) ----------------
__global__ __launch_bounds__(256) void convert_wo(const float* __restrict__ wo,
                                                  _Float16* __restrict__ dst) {
  int i = (blockIdx.x * 256 + threadIdx.x) * 4;
  float4 v = *(const float4*)(wo + i);
  half4 h;
  h[0] = (_Float16)v.x; h[1] = (_Float16)v.y;
  h[2] = (_Float16)v.z; h[3] = (_Float16)v.w;
  *(half4*)(dst + i) = h;
}

// ---------------- fused QKV projection GEMM v6 (unchanged from r9: best known, 66us) ----------------
__global__ __launch_bounds__(256, 3) void qkv_gemm(
    const float* __restrict__ Qf, const float* __restrict__ Kf, const float* __restrict__ Vf,
    const _Float16* __restrict__ wh,
    const float* __restrict__ bq, const float* __restrict__ bk, const float* __restrict__ bv,
    _Float16* __restrict__ qo, _Float16* __restrict__ ko, _Float16* __restrict__ vt) {
  __shared__ __align__(16) _Float16 Asb[3][128 * 32];  // 8KB x3
  __shared__ __align__(16) _Float16 Bsb[3][128 * 32];  // 8KB x3
  const int tid = threadIdx.x;
  const int wave = tid >> 6, lane = tid & 63;
  const int m15 = lane & 15, quad = lane >> 4;
  const int m0 = blockIdx.x * 128;
  const int y = blockIdx.y;
  const int sel = (y < 8) ? 2 : (y < 16) ? 0 : 1;  // v first, then q, then k
  const int n0 = (y & 7) * 128;
  const float* Ag = (sel == 0) ? Qf : (sel == 1) ? Kf : Vf;
  const _Float16* Wg = wh + (size_t)sel * (DMODEL * DMODEL);
  const float* bias = (sel == 0) ? bq : (sel == 1) ? bk : bv;

  const int wm = (wave & 1) * 64, wn = (wave >> 1) * 64;

  const int sr = tid >> 1, sc16 = (tid & 1) * 16;
  const int g0 = (tid & 1) * 2, asw = (sr >> 1) & 3;
  const int b_r = lane >> 2, b_g = (lane & 3) ^ ((lane >> 3) & 3);
  const int ra = ((quad ^ ((m15 >> 1) & 3)) << 4);

  f32x4 acc[4][4];
#pragma unroll
  for (int i = 0; i < 4; i++)
#pragma unroll
    for (int j = 0; j < 4; j++) {
      f32x4 z = {0.f, 0.f, 0.f, 0.f};
      acc[i][j] = z;
    }

  const float* ap = Ag + (size_t)(m0 + sr) * DMODEL + sc16;

  auto loadA = [&](int kk, float4 (&s)[4]) {
    const float* p = ap + kk;
    s[0] = ((const float4*)p)[0];
    s[1] = ((const float4*)p)[1];
    s[2] = ((const float4*)p)[2];
    s[3] = ((const float4*)p)[3];
  };
  auto writeA = [&](const float4 (&s)[4], int nb) {
    half8 h0, h1;
    h0[0] = (_Float16)s[0].x; h0[1] = (_Float16)s[0].y; h0[2] = (_Float16)s[0].z; h0[3] = (_Float16)s[0].w;
    h0[4] = (_Float16)s[1].x; h0[5] = (_Float16)s[1].y; h0[6] = (_Float16)s[1].z; h0[7] = (_Float16)s[1].w;
    h1[0] = (_Float16)s[2].x; h1[1] = (_Float16)s[2].y; h1[2] = (_Float16)s[2].z; h1[3] = (_Float16)s[2].w;
    h1[4] = (_Float16)s[3].x; h1[5] = (_Float16)s[3].y; h1[6] = (_Float16)s[3].z; h1[7] = (_Float16)s[3].w;
    char* rb = (char*)&Asb[nb][0] + sr * 64;
    *(half8*)(rb + ((g0 ^ asw) << 4)) = h0;
    *(half8*)(rb + (((g0 + 1) ^ asw) << 4)) = h1;
  };
  auto issueB = [&](int kk, int nb) {
#pragma unroll
    for (int p = 0; p < 2; p++) {
      int row = (p * 4 + wave) * 16 + b_r;
      async_copy16(Wg + (size_t)(n0 + row) * DMODEL + kk + b_g * 8,
                   (char*)&Bsb[nb][0] + p * 4096 + wave * 1024);
    }
  };
  auto compute = [&](int m3) {
    const char* ab = (const char*)&Asb[m3][0];
    const char* bb = (const char*)&Bsb[m3][0];
    half8 af[4], bf[4];
#pragma unroll
    for (int i = 0; i < 4; i++)
      af[i] = *(const half8*)(ab + (wm + i * 16 + m15) * 64 + ra);
#pragma unroll
    for (int j = 0; j < 4; j++)
      bf[j] = *(const half8*)(bb + (wn + j * 16 + m15) * 64 + ra);
#pragma unroll
    for (int i = 0; i < 4; i++)
#pragma unroll
      for (int j = 0; j < 4; j++)
        acc[i][j] = __builtin_amdgcn_mfma_f32_16x16x32_f16(af[i], bf[j], acc[i][j], 0, 0, 0);
  };

  float4 s0[4], s1[4], s2[4];

  issueB(0, 0);
  loadA(0, s0);
  issueB(32, 1);
  loadA(32, s1);
  loadA(64, s2);
  WAIT_VMCNT(10);
  writeA(s0, 0);
  WAIT_LGKM0();
  RAW_BARRIER();

  auto body = [&](int kt, int m3, int bB, int bW, float4 (&ld)[4], const float4 (&wr)[4],
                  int mode) {
    if (mode == 0) {
      issueB((kt + 2) * 32, bB);
      loadA((kt + 3) * 32, ld);
    } else if (mode == 1) {
      issueB((kt + 2) * 32, bB);
    }
    compute(m3);
    if (mode == 3) return;
    if (mode == 0) { WAIT_VMCNT(10); }
    else if (mode == 1) { WAIT_VMCNT(6); }
    else { WAIT_VMCNT(0); }
    writeA(wr, bW);
    WAIT_LGKM0();
    RAW_BARRIER();
  };

#pragma unroll 1
  for (int k3 = 0; k3 < 27; k3 += 3) {
    body(k3 + 0, 0, 2, 1, s0, s1, 0);
    body(k3 + 1, 1, 0, 2, s1, s2, 0);
    body(k3 + 2, 2, 1, 0, s2, s0, 0);
  }
  body(27, 0, 2, 1, s0, s1, 0);
  body(28, 1, 0, 2, s1, s2, 0);
  body(29, 2, 1, 0, s2, s0, 1);
  body(30, 0, 0, 1, s0, s1, 2);
  body(31, 1, 0, 0, s0, s0, 3);

  if (sel != 2) {
    _Float16* outp = (sel == 0) ? qo : ko;
    const float scale = (sel == 0) ? (0.125f * LOG2E) : 1.0f;
#pragma unroll
    for (int i = 0; i < 4; i++) {
#pragma unroll
      for (int j = 0; j < 4; j++) {
        int gn = n0 + wn + j * 16 + m15;
        float bb = bias[gn];
#pragma unroll
        for (int r = 0; r < 4; r++) {
          int gm = m0 + wm + i * 16 + quad * 4 + r;
          outp[(size_t)gm * DMODEL + gn] = (_Float16)((acc[i][j][r] + bb) * scale);
        }
      }
    }
  } else {
#pragma unroll
    for (int i = 0; i < 4; i++) {
      int gm0 = m0 + wm + i * 16 + quad * 4;
      int b = gm0 >> 11, s = gm0 & 2047;
#pragma unroll
      for (int j = 0; j < 4; j++) {
        int gn = n0 + wn + j * 16 + m15;
        int h = gn >> 6, dk = gn & 63;
        float bb = bias[gn];
        half4 hv;
        hv[0] = (_Float16)(acc[i][j][0] + bb);
        hv[1] = (_Float16)(acc[i][j][1] + bb);
        hv[2] = (_Float16)(acc[i][j][2] + bb);
        hv[3] = (_Float16)(acc[i][j][3] + bb);
        *(half4*)(vt + ((size_t)(b * 16 + h) * 64 + dk) * 2048 + s) = hv;
      }
    }
  }
}

// ---------------- flash attention v6: K-only LDS (16KB), V read direct from L2 ----------------
// V^T block (256KB per (b,h)) is L2-resident; staging it through LDS was pure overhead
// (guide m169: dropping V-staging at L2-fit = +26%). V A-fragments load straight from vt
// (quads cover 64B/row contiguous). LDS: K double-buffer only -> 16.25KB -> block cap 9,
// grid 4/CU = 16 waves (was 12). Compute body otherwise identical to verified r4 kernel.
__global__ __launch_bounds__(256) void attn_kernel(const _Float16* __restrict__ qh,
                                                   const _Float16* __restrict__ kh,
                                                   const _Float16* __restrict__ vt,
                                                   _Float16* __restrict__ ctx) {
  // [0,16384) Ks[2][64][64]; epilogue reuses [0,16384) as Ored[64][64] + Lred at 16384.
  __shared__ __align__(16) char smem[16640];
  const int tid = threadIdx.x;
  const int wave = tid >> 6, lane = tid & 63;
  const int m15 = lane & 15, qd = lane >> 4;
  const int wq = wave >> 1, ws = wave & 1;
  const int q0 = blockIdx.x * 64;
  const int h = blockIdx.y, b = blockIdx.z;
  const size_t base = (size_t)b * S_LEN * DMODEL + (size_t)h * DHEAD;  // q/k/ctx base
  const size_t vbase = (size_t)(b * 16 + h) * 64 * 2048;               // vt base

  // Q fragments (pre-scaled by 0.125*log2e): B-layout n=m15 (q row), k=qd*8+j (dk)
  half8 qf[2][2];
#pragma unroll
  for (int qt = 0; qt < 2; qt++) {
    const _Float16* qp = qh + base + (size_t)(q0 + wq * 32 + qt * 16 + m15) * DMODEL + qd * 8;
    qf[qt][0] = *(const half8*)qp;
    qf[qt][1] = *(const half8*)(qp + 32);
  }

  // K staging: per-lane pre-swizzled global source (16B granule: slot s8 holds logical s8^l8)
  const int l8 = lane >> 3, s8 = lane & 7;
  const int swz = (s8 ^ l8) * 8;
  const _Float16* ksrc = kh + base + (size_t)(wave * 8 + l8) * DMODEL + swz;
  char* kdst = smem + wave * 1024;

  // K read-side swizzled granule offset; V direct-global row base (A-frag: dk row, s' col)
  const int kgr = ((qd ^ (m15 & 7)) << 4);
  const int krow = ws * 32 + m15;
  const _Float16* vrow = vt + vbase + (size_t)m15 * 2048 + ws * 32 + qd * 8;

  f32x4 acc[4][2];  // [dk-tile][q-tile] partial O^T over this wave's 32-s' slice
#pragma unroll
  for (int i = 0; i < 4; i++)
#pragma unroll
    for (int j = 0; j < 2; j++) { f32x4 z = {0.f, 0.f, 0.f, 0.f}; acc[i][j] = z; }
  float ls[2] = {0.f, 0.f};

  // prologue: stage K tile 0 into buf 0
#pragma unroll
  for (int p = 0; p < 2; p++)
    async_copy16(ksrc + (size_t)(p * 32) * DMODEL, kdst + p * 4096);
  __syncthreads();

  for (int it = 0; it < 32; it++) {
    const int buf = it & 1;
    if (it < 31) {  // stage K tile it+1 into buf^1 (latency hidden under compute + TLP)
      const int kv = (it + 1) * 64;
#pragma unroll
      for (int p = 0; p < 2; p++)
        async_copy16(ksrc + (size_t)(kv + p * 32) * DMODEL, kdst + (buf ^ 1) * 8192 + p * 4096);
    }
    const char* kb = smem + buf * 8192;
    const int kv0 = it * 64;

    // ---- K slice fragments: A-layout row = ws*32+16t+m15 (s'), k=qd*8+j (dk) ----
    half8 kf[2][2];
#pragma unroll
    for (int t = 0; t < 2; t++) {
      kf[t][0] = *(const half8*)(kb + (krow + 16 * t) * 128 + kgr);
      kf[t][1] = *(const half8*)(kb + (krow + 16 * t) * 128 + (kgr ^ 64));
    }

    // ---- QK^T: sc[t][qt] = P[s'_slice=16t+qd*4+r][q=qt*16+m15] ----
    f32x4 sc[2][2];
#pragma unroll
    for (int t = 0; t < 2; t++)
#pragma unroll
      for (int qt = 0; qt < 2; qt++) {
        f32x4 z = {0.f, 0.f, 0.f, 0.f};
        sc[t][qt] = __builtin_amdgcn_mfma_f32_16x16x32_f16(kf[t][0], qf[qt][0], z, 0, 0, 0);
        sc[t][qt] = __builtin_amdgcn_mfma_f32_16x16x32_f16(kf[t][1], qf[qt][1], sc[t][qt], 0, 0, 0);
      }

    // ---- V A-fragments direct from global (L2-hot): row dk=td*16+m15, col kv0+ws*32+qd*8 ----
    half8 vf0 = *(const half8*)(vrow + kv0);
    half8 vf1 = *(const half8*)(vrow + 16 * 2048 + kv0);
    half8 vf2 = *(const half8*)(vrow + 32 * 2048 + kv0);
    half8 vf3 = *(const half8*)(vrow + 48 * 2048 + kv0);

    // ---- p = exp2(score); lane-local row sums; pack pairs to half2 words ----
    int pk[2][2][2];
#pragma unroll
    for (int t = 0; t < 2; t++)
#pragma unroll
      for (int qt = 0; qt < 2; qt++) {
        float e0 = __builtin_amdgcn_exp2f(sc[t][qt][0]);
        float e1 = __builtin_amdgcn_exp2f(sc[t][qt][1]);
        float e2 = __builtin_amdgcn_exp2f(sc[t][qt][2]);
        float e3 = __builtin_amdgcn_exp2f(sc[t][qt][3]);
        ls[qt] += (e0 + e1) + (e2 + e3);
        pk[t][qt][0] = __builtin_bit_cast(int, __builtin_amdgcn_cvt_pkrtz(e0, e1));
        pk[t][qt][1] = __builtin_bit_cast(int, __builtin_amdgcn_cvt_pkrtz(e2, e3));
      }

    // ---- butterfly (validated r2/r4): lane holds P[s'_slice=qd*8+jj][q] = PV B-fragment ----
    half8 pA[2];
#pragma unroll
    for (int qt = 0; qt < 2; qt++) {
      i32x4 fh;
#pragma unroll
      for (int p = 0; p < 2; p++) {
        auto s1 = __builtin_amdgcn_permlane32_swap(pk[0][qt][p], pk[1][qt][p], false, false);
        auto s2 = __builtin_amdgcn_permlane16_swap(s1[0], s1[1], false, false);
        fh[p] = (int)s2[0];
        fh[2 + p] = (int)s2[1];
      }
      pA[qt] = __builtin_bit_cast(half8, fh);
    }

    // ---- PV: acc[td][qt] += V^T[dk slice][s' slice] x P ----
#pragma unroll
    for (int qt = 0; qt < 2; qt++) {
      acc[0][qt] = __builtin_amdgcn_mfma_f32_16x16x32_f16(vf0, pA[qt], acc[0][qt], 0, 0, 0);
      acc[1][qt] = __builtin_amdgcn_mfma_f32_16x16x32_f16(vf1, pA[qt], acc[1][qt], 0, 0, 0);
      acc[2][qt] = __builtin_amdgcn_mfma_f32_16x16x32_f16(vf2, pA[qt], acc[2][qt], 0, 0, 0);
      acc[3][qt] = __builtin_amdgcn_mfma_f32_16x16x32_f16(vf3, pA[qt], acc[3][qt], 0, 0, 0);
    }
    __syncthreads();  // drains this wave's K-DMA + all waves done reading buf
  }

  // ---- cross-ws reduction through LDS (K buffer dead after final barrier) ----
  float* Ored = (float*)smem;            // [64 q][64] f32 (epilogue-only; once per kernel)
  float* Lred = (float*)(smem + 16384);  // [64 q] f32 (ws=1 partials)

#pragma unroll
  for (int qt = 0; qt < 2; qt++) {
    ls[qt] += __shfl_xor(ls[qt], 16);
    ls[qt] += __shfl_xor(ls[qt], 32);
  }

  if (ws == 1) {
#pragma unroll
    for (int qt = 0; qt < 2; qt++) {
      int q = wq * 32 + qt * 16 + m15;
      if (qd == 0) Lred[q] = ls[qt];
#pragma unroll
      for (int td = 0; td < 4; td++)
        *(f32x4*)&Ored[q * 64 + td * 16 + qd * 4] = acc[td][qt];
    }
  }
  __syncthreads();

  if (ws == 0) {
#pragma unroll
    for (int qt = 0; qt < 2; qt++) {
      int q = wq * 32 + qt * 16 + m15;
      const float inv = 1.0f / (ls[qt] + Lred[q]);
#pragma unroll
      for (int td = 0; td < 4; td++) {
        f32x4 o = acc[td][qt] + *(const f32x4*)&Ored[q * 64 + td * 16 + qd * 4];
        half4 hv;
#pragma unroll
        for (int r = 0; r < 4; r++) hv[r] = (_Float16)(o[r] * inv);
        *(half4*)(ctx + base + (size_t)(q0 + q) * DMODEL + td * 16 + qd * 4) = hv;
      }
    }
  }
}

// ---------------- output projection v5: 64x64xBK64, grid(64,16)=4 blocks/CU ----------------
// Occupancy was the binder: old (64,8) grid = 2 blocks/CU, 8 waves. Now 1024 blocks = 4/CU,
// 16 iterations of 8 MFMA + 8 b128 per wave (denser phases). 2-buf, stage-next-at-top,
// one __syncthreads per iter. LDS 128B rows with the r4-verified g^(row&7) swizzle class.
__global__ __launch_bounds__(256) void out_gemm(const _Float16* __restrict__ ch,
                                                const _Float16* __restrict__ who,
                                                const float* __restrict__ bo,
                                                float* __restrict__ out) {
  __shared__ __align__(16) _Float16 As[2][64 * 64];  // 8KB x2
  __shared__ __align__(16) _Float16 Bs[2][64 * 64];  // 8KB x2
  const int tid = threadIdx.x;
  const int wave = tid >> 6, lane = tid & 63;
  const int m15 = lane & 15, quad = lane >> 4;
  const int m0 = blockIdx.x * 64, n0 = blockIdx.y * 64;
  const int wm = (wave & 1) * 32, wn = (wave >> 1) * 32;

  // staging: per-lane pre-swizzled source (128B rows, 8 granules; slot s8 = logical s8^l8)
  const int l8 = lane >> 3, s8 = lane & 7;
  const int swz = (s8 ^ l8) * 8;
  const _Float16* asrc = ch + (size_t)(m0 + wave * 8 + l8) * DMODEL + swz;
  const _Float16* bsrc = who + (size_t)(n0 + wave * 8 + l8) * DMODEL + swz;
  char* adst = (char*)&As[0][0] + wave * 1024;
  char* bdst = (char*)&Bs[0][0] + wave * 1024;

  // read-side: row & 7 == m15 & 7; granule g = h*4 + quad
  const int rg0 = ((quad ^ (m15 & 7)) << 4);

  f32x4 acc[2][2];
#pragma unroll
  for (int i = 0; i < 2; i++)
#pragma unroll
    for (int j = 0; j < 2; j++) {
      f32x4 z = {0.f, 0.f, 0.f, 0.f};
      acc[i][j] = z;
    }

  auto stage = [&](int kk, int bufi) {  // 4 DMA issues: 2 A + 2 B
#pragma unroll
    for (int p = 0; p < 2; p++) {
      async_copy16(asrc + (size_t)(p * 32) * DMODEL + kk, adst + bufi * 8192 + p * 4096);
      async_copy16(bsrc + (size_t)(p * 32) * DMODEL + kk, bdst + bufi * 8192 + p * 4096);
    }
  };

  stage(0, 0);
  __syncthreads();

  for (int kt = 0; kt < 16; kt++) {
    const int buf = kt & 1;
    if (kt < 15) stage((kt + 1) * 64, buf ^ 1);
    const char* ab = (const char*)&As[buf][0];
    const char* bb = (const char*)&Bs[buf][0];
    half8 af[2][2], bf[2][2];
#pragma unroll
    for (int i = 0; i < 2; i++) {
      af[i][0] = *(const half8*)(ab + (wm + i * 16 + m15) * 128 + rg0);
      af[i][1] = *(const half8*)(ab + (wm + i * 16 + m15) * 128 + (rg0 ^ 64));
    }
#pragma unroll
    for (int j = 0; j < 2; j++) {
      bf[j][0] = *(const half8*)(bb + (wn + j * 16 + m15) * 128 + rg0);
      bf[j][1] = *(const half8*)(bb + (wn + j * 16 + m15) * 128 + (rg0 ^ 64));
    }
#pragma unroll
    for (int i = 0; i < 2; i++)
#pragma unroll
      for (int j = 0; j < 2; j++) {
        acc[i][j] = __builtin_amdgcn_mfma_f32_16x16x32_f16(af[i][0], bf[j][0], acc[i][j], 0, 0, 0);
        acc[i][j] = __builtin_amdgcn_mfma_f32_16x16x32_f16(af[i][1], bf[j][1], acc[i][j], 0, 0, 0);
      }
    __syncthreads();
  }
#pragma unroll
  for (int i = 0; i < 2; i++) {
#pragma unroll
    for (int j = 0; j < 2; j++) {
      int gn = n0 + wn + j * 16 + m15;
      float bb = bo[gn];
#pragma unroll
      for (int r = 0; r < 4; r++) {
        int gm = m0 + wm + i * 16 + quad * 4 + r;
        out[(size_t)gm * DMODEL + gn] = acc[i][j][r] + bb;
      }
    }
  }
}

extern "C" void kernel_launch(void* const* d_in, const int* in_sizes, int n_in,
                              void* d_out, int out_size, void* d_ws, size_t ws_size,
                              hipStream_t stream) {
  (void)in_sizes; (void)n_in; (void)out_size; (void)ws_size;
  const float* Q  = (const float*)d_in[0];
  const float* K  = (const float*)d_in[1];
  const float* V  = (const float*)d_in[2];
  const float* wq = (const float*)d_in[3];
  const float* bq = (const float*)d_in[4];
  const float* wk = (const float*)d_in[5];
  const float* bk = (const float*)d_in[6];
  const float* wv = (const float*)d_in[7];
  const float* bv = (const float*)d_in[8];
  const float* wo = (const float*)d_in[9];
  const float* bo = (const float*)d_in[10];
  float* out = (float*)d_out;

  // Scratch plan (16 MB d_ws + d_out reuse), timeline:
  //   qh, kh (fp16, 8 MB each)  -> inside d_out (dead before out_gemm writes fp32 there)
  //   vt (fp16 transposed, 8MB) -> ws[0:8M)   -- alive qkv..attn
  //   wh (fp16 wq|wk|wv, 6 MB)  -> ws[8M:14M) -- alive only during qkv_gemm
  //   ch (fp16 ctx, 8 MB)       -> ws[8M:16M) -- written by attn (overlays wh, disjoint in time)
  //   who (fp16 wo, 2 MB)       -> ws[0:2M)   -- written AFTER attn (overlays dead vt)
  _Float16* qh = (_Float16*)d_out;
  _Float16* kh = qh + (size_t)4194304;
  _Float16* vt = (_Float16*)d_ws;
  _Float16* wh = vt + (size_t)4194304;
  _Float16* ch = vt + (size_t)4194304;
  _Float16* who = (_Float16*)d_ws;

  convert_w<<<dim3(1024, 3), 256, 0, stream>>>(wq, wk, wv, wh);
  qkv_gemm<<<dim3(32, 24), 256, 0, stream>>>(Q, K, V, wh, bq, bk, bv, qh, kh, vt);
  attn_kernel<<<dim3(32, 16, 2), 256, 0, stream>>>(qh, kh, vt, ch);
  convert_wo<<<dim3(1024), 256, 0, stream>>>(wo, who);
  out_gemm<<<dim3(64, 16), 256, 0, stream>>>(ch, who, bo, out);
}

// Round 11
// 232.138 us; speedup vs baseline: 1.1277x; 1.1277x over previous
//
#include <hip/hip_runtime.h>

// Problem constants: B=2, S=2048, D=1024, H=16, DK=64
#define S_LEN 2048
#define DMODEL 1024
#define DHEAD 64

typedef _Float16 half8 __attribute__((ext_vector_type(8)));
typedef _Float16 half4 __attribute__((ext_vector_type(4)));
typedef float f32x4 __attribute__((ext_vector_type(4)));
typedef int i32x4 __attribute__((ext_vector_type(4)));

#define LOG2E 1.4426950408889634f

// async global->LDS, 16B per lane; LDS dest is wave-uniform base, HW writes lane i at base+16*i.
__device__ __forceinline__ void async_copy16(const void* g, void* l) {
  __builtin_amdgcn_global_load_lds((__attribute__((address_space(1))) const void*)g,
                                   (__attribute__((address_space(3))) void*)l,
                                   16, 0, 0);
}

#define WAIT_VMCNT(N) asm volatile("s_waitcnt vmcnt(" #N ")" ::: "memory")
#define WAIT_LGKM0() asm volatile("s_waitcnt lgkmcnt(0)" ::: "memory")
#define RAW_BARRIER() asm volatile("s_barrier" ::: "memory")

// ---------------- convert wq,wk,wv fp32 -> fp16 ----------------
__global__ __launch_bounds__(256) void convert_w(const float* __restrict__ wq,
                                                 const float* __restrict__ wk,
                                                 const float* __restrict__ wv,
                                                 _Float16* __restrict__ dst) {
  const float* src = (blockIdx.y == 0) ? wq : (blockIdx.y == 1) ? wk : wv;
  _Float16* d = dst + (size_t)blockIdx.y * (DMODEL * DMODEL);
  int i = (blockIdx.x * 256 + threadIdx.x) * 4;
  float4 v = *(const float4*)(src + i);
  half4 h;
  h[0] = (_Float16)v.x; h[1] = (_Float16)v.y;
  h[2] = (_Float16)v.z; h[3] = (_Float16)v.w;
  *(half4*)(d + i) = h;
}

// ---------------- convert wo fp32 -> fp16 (runs after attn; vt slot is dead) ----------------
__global__ __launch_bounds__(256) void convert_wo(const float* __restrict__ wo,
                                                  _Float16* __restrict__ dst) {
  int i = (blockIdx.x * 256 + threadIdx.x) * 4;
  float4 v = *(const float4*)(wo + i);
  half4 h;
  h[0] = (_Float16)v.x; h[1] = (_Float16)v.y;
  h[2] = (_Float16)v.z; h[3] = (_Float16)v.w;
  *(half4*)(dst + i) = h;
}

// ---------------- fused QKV projection GEMM v6 (unchanged from r9: best known, 66us) ----------------
__global__ __launch_bounds__(256, 3) void qkv_gemm(
    const float* __restrict__ Qf, const float* __restrict__ Kf, const float* __restrict__ Vf,
    const _Float16* __restrict__ wh,
    const float* __restrict__ bq, const float* __restrict__ bk, const float* __restrict__ bv,
    _Float16* __restrict__ qo, _Float16* __restrict__ ko, _Float16* __restrict__ vt) {
  __shared__ __align__(16) _Float16 Asb[3][128 * 32];  // 8KB x3
  __shared__ __align__(16) _Float16 Bsb[3][128 * 32];  // 8KB x3
  const int tid = threadIdx.x;
  const int wave = tid >> 6, lane = tid & 63;
  const int m15 = lane & 15, quad = lane >> 4;
  const int m0 = blockIdx.x * 128;
  const int y = blockIdx.y;
  const int sel = (y < 8) ? 2 : (y < 16) ? 0 : 1;  // v first, then q, then k
  const int n0 = (y & 7) * 128;
  const float* Ag = (sel == 0) ? Qf : (sel == 1) ? Kf : Vf;
  const _Float16* Wg = wh + (size_t)sel * (DMODEL * DMODEL);
  const float* bias = (sel == 0) ? bq : (sel == 1) ? bk : bv;

  const int wm = (wave & 1) * 64, wn = (wave >> 1) * 64;

  const int sr = tid >> 1, sc16 = (tid & 1) * 16;
  const int g0 = (tid & 1) * 2, asw = (sr >> 1) & 3;
  const int b_r = lane >> 2, b_g = (lane & 3) ^ ((lane >> 3) & 3);
  const int ra = ((quad ^ ((m15 >> 1) & 3)) << 4);

  f32x4 acc[4][4];
#pragma unroll
  for (int i = 0; i < 4; i++)
#pragma unroll
    for (int j = 0; j < 4; j++) {
      f32x4 z = {0.f, 0.f, 0.f, 0.f};
      acc[i][j] = z;
    }

  const float* ap = Ag + (size_t)(m0 + sr) * DMODEL + sc16;

  auto loadA = [&](int kk, float4 (&s)[4]) {
    const float* p = ap + kk;
    s[0] = ((const float4*)p)[0];
    s[1] = ((const float4*)p)[1];
    s[2] = ((const float4*)p)[2];
    s[3] = ((const float4*)p)[3];
  };
  auto writeA = [&](const float4 (&s)[4], int nb) {
    half8 h0, h1;
    h0[0] = (_Float16)s[0].x; h0[1] = (_Float16)s[0].y; h0[2] = (_Float16)s[0].z; h0[3] = (_Float16)s[0].w;
    h0[4] = (_Float16)s[1].x; h0[5] = (_Float16)s[1].y; h0[6] = (_Float16)s[1].z; h0[7] = (_Float16)s[1].w;
    h1[0] = (_Float16)s[2].x; h1[1] = (_Float16)s[2].y; h1[2] = (_Float16)s[2].z; h1[3] = (_Float16)s[2].w;
    h1[4] = (_Float16)s[3].x; h1[5] = (_Float16)s[3].y; h1[6] = (_Float16)s[3].z; h1[7] = (_Float16)s[3].w;
    char* rb = (char*)&Asb[nb][0] + sr * 64;
    *(half8*)(rb + ((g0 ^ asw) << 4)) = h0;
    *(half8*)(rb + (((g0 + 1) ^ asw) << 4)) = h1;
  };
  auto issueB = [&](int kk, int nb) {
#pragma unroll
    for (int p = 0; p < 2; p++) {
      int row = (p * 4 + wave) * 16 + b_r;
      async_copy16(Wg + (size_t)(n0 + row) * DMODEL + kk + b_g * 8,
                   (char*)&Bsb[nb][0] + p * 4096 + wave * 1024);
    }
  };
  auto compute = [&](int m3) {
    const char* ab = (const char*)&Asb[m3][0];
    const char* bb = (const char*)&Bsb[m3][0];
    half8 af[4], bf[4];
#pragma unroll
    for (int i = 0; i < 4; i++)
      af[i] = *(const half8*)(ab + (wm + i * 16 + m15) * 64 + ra);
#pragma unroll
    for (int j = 0; j < 4; j++)
      bf[j] = *(const half8*)(bb + (wn + j * 16 + m15) * 64 + ra);
#pragma unroll
    for (int i = 0; i < 4; i++)
#pragma unroll
      for (int j = 0; j < 4; j++)
        acc[i][j] = __builtin_amdgcn_mfma_f32_16x16x32_f16(af[i], bf[j], acc[i][j], 0, 0, 0);
  };

  float4 s0[4], s1[4], s2[4];

  issueB(0, 0);
  loadA(0, s0);
  issueB(32, 1);
  loadA(32, s1);
  loadA(64, s2);
  WAIT_VMCNT(10);
  writeA(s0, 0);
  WAIT_LGKM0();
  RAW_BARRIER();

  auto body = [&](int kt, int m3, int bB, int bW, float4 (&ld)[4], const float4 (&wr)[4],
                  int mode) {
    if (mode == 0) {
      issueB((kt + 2) * 32, bB);
      loadA((kt + 3) * 32, ld);
    } else if (mode == 1) {
      issueB((kt + 2) * 32, bB);
    }
    compute(m3);
    if (mode == 3) return;
    if (mode == 0) { WAIT_VMCNT(10); }
    else if (mode == 1) { WAIT_VMCNT(6); }
    else { WAIT_VMCNT(0); }
    writeA(wr, bW);
    WAIT_LGKM0();
    RAW_BARRIER();
  };

#pragma unroll 1
  for (int k3 = 0; k3 < 27; k3 += 3) {
    body(k3 + 0, 0, 2, 1, s0, s1, 0);
    body(k3 + 1, 1, 0, 2, s1, s2, 0);
    body(k3 + 2, 2, 1, 0, s2, s0, 0);
  }
  body(27, 0, 2, 1, s0, s1, 0);
  body(28, 1, 0, 2, s1, s2, 0);
  body(29, 2, 1, 0, s2, s0, 1);
  body(30, 0, 0, 1, s0, s1, 2);
  body(31, 1, 0, 0, s0, s0, 3);

  if (sel != 2) {
    _Float16* outp = (sel == 0) ? qo : ko;
    const float scale = (sel == 0) ? (0.125f * LOG2E) : 1.0f;
#pragma unroll
    for (int i = 0; i < 4; i++) {
#pragma unroll
      for (int j = 0; j < 4; j++) {
        int gn = n0 + wn + j * 16 + m15;
        float bb = bias[gn];
#pragma unroll
        for (int r = 0; r < 4; r++) {
          int gm = m0 + wm + i * 16 + quad * 4 + r;
          outp[(size_t)gm * DMODEL + gn] = (_Float16)((acc[i][j][r] + bb) * scale);
        }
      }
    }
  } else {
#pragma unroll
    for (int i = 0; i < 4; i++) {
      int gm0 = m0 + wm + i * 16 + quad * 4;
      int b = gm0 >> 11, s = gm0 & 2047;
#pragma unroll
      for (int j = 0; j < 4; j++) {
        int gn = n0 + wn + j * 16 + m15;
        int h = gn >> 6, dk = gn & 63;
        float bb = bias[gn];
        half4 hv;
        hv[0] = (_Float16)(acc[i][j][0] + bb);
        hv[1] = (_Float16)(acc[i][j][1] + bb);
        hv[2] = (_Float16)(acc[i][j][2] + bb);
        hv[3] = (_Float16)(acc[i][j][3] + bb);
        *(half4*)(vt + ((size_t)(b * 16 + h) * 64 + dk) * 2048 + s) = hv;
      }
    }
  }
}

// ---------------- flash attention v5 (REVERTED to r9: triple-buffer counted-vmcnt) ----------------
// r10's V-direct-from-global regressed (-30us): V loads had zero latency cover. This version
// stages K AND V via DMA 2 tiles ahead (counted vmcnt(4), never drained mid-loop).
__global__ __launch_bounds__(256) void attn_kernel(const _Float16* __restrict__ qh,
                                                   const _Float16* __restrict__ kh,
                                                   const _Float16* __restrict__ vt,
                                                   _Float16* __restrict__ ctx) {
  // [0,24K) Ks[3][64][64], [24K,48K) Vs[3][64][64]; epilogue reuses [0,17664) as Ored/Lred.
  __shared__ __align__(16) char smem[49152];
  const int tid = threadIdx.x;
  const int wave = tid >> 6, lane = tid & 63;
  const int m15 = lane & 15, qd = lane >> 4;
  const int wq = wave >> 1, ws = wave & 1;
  const int q0 = blockIdx.x * 64;
  const int h = blockIdx.y, b = blockIdx.z;
  const size_t base = (size_t)b * S_LEN * DMODEL + (size_t)h * DHEAD;  // q/k/ctx base
  const size_t vbase = (size_t)(b * 16 + h) * 64 * 2048;               // vt base

  // Q fragments (pre-scaled by 0.125*log2e): B-layout n=m15 (q row), k=qd*8+j (dk)
  half8 qf[2][2];
#pragma unroll
  for (int qt = 0; qt < 2; qt++) {
    const _Float16* qp = qh + base + (size_t)(q0 + wq * 32 + qt * 16 + m15) * DMODEL + qd * 8;
    qf[qt][0] = *(const half8*)qp;
    qf[qt][1] = *(const half8*)(qp + 32);
  }

  // staging: per-lane pre-swizzled global sources (16B granule: slot s8 holds logical s8^l8)
  const int l8 = lane >> 3, s8 = lane & 7;
  const int swz = (s8 ^ l8) * 8;  // halfs within a 64-half row
  const _Float16* ksrc = kh + base + (size_t)(wave * 8 + l8) * DMODEL + swz;
  const _Float16* vsrc = vt + vbase + (size_t)(wave * 8 + l8) * S_LEN + swz;

  // read-side swizzled granule byte offsets (row&7 == m15&7 for all read rows)
  const int kgr = ((qd ^ (m15 & 7)) << 4);             // K: dk granule G=qd (dk 0..31)
  const int vgr = (((ws * 4 + qd) ^ (m15 & 7)) << 4);  // V: s' granule G=ws*4+qd
  const int krow = ws * 32 + m15;                      // + 16t

  auto stage = [&](int tile, int bufi) {  // 4 DMA issues: 2 K + 2 V (this wave's chunks)
    const int kv = tile * 64;
    char* kd = smem + bufi * 8192 + wave * 1024;
    char* vd = smem + 24576 + bufi * 8192 + wave * 1024;
#pragma unroll
    for (int p = 0; p < 2; p++) {
      async_copy16(ksrc + (size_t)(kv + p * 32) * DMODEL, kd + p * 4096);
      async_copy16(vsrc + (size_t)(p * 32) * S_LEN + kv, vd + p * 4096);
    }
  };

  f32x4 acc[4][2];  // [dk-tile][q-tile] partial O^T over this wave's 32-s' slice
#pragma unroll
  for (int i = 0; i < 4; i++)
#pragma unroll
    for (int j = 0; j < 2; j++) { f32x4 z = {0.f, 0.f, 0.f, 0.f}; acc[i][j] = z; }
  float ls[2] = {0.f, 0.f};  // per-lane partial row sums (q = qt*16+m15)

  // prologue: tiles 0,1 staged; tile 1's 4 loads stay in flight across the barrier
  stage(0, 0);
  stage(1, 1);
  WAIT_VMCNT(4);  // tile 0 landed
  RAW_BARRIER();

  int bcur = 0, bnxt = 2;  // it%3, (it+2)%3
  for (int it = 0; it < 32; it++) {
    if (it < 30) stage(it + 2, bnxt);  // target buf last read at it-1 (behind barrier)
    const char* kb = smem + bcur * 8192;
    const char* vb = smem + 24576 + bcur * 8192;

    // ---- K slice fragments: A-layout row = ws*32+16t+m15 (s'), k=qd*8+j (dk) ----
    half8 kf[2][2];
#pragma unroll
    for (int t = 0; t < 2; t++) {
      kf[t][0] = *(const half8*)(kb + (krow + 16 * t) * 128 + kgr);
      kf[t][1] = *(const half8*)(kb + (krow + 16 * t) * 128 + (kgr ^ 64));
    }

    // ---- QK^T: sc[t][qt] = P[s'_slice=16t+qd*4+r][q=qt*16+m15] ----
    f32x4 sc[2][2];
#pragma unroll
    for (int t = 0; t < 2; t++)
#pragma unroll
      for (int qt = 0; qt < 2; qt++) {
        f32x4 z = {0.f, 0.f, 0.f, 0.f};
        sc[t][qt] = __builtin_amdgcn_mfma_f32_16x16x32_f16(kf[t][0], qf[qt][0], z, 0, 0, 0);
        sc[t][qt] = __builtin_amdgcn_mfma_f32_16x16x32_f16(kf[t][1], qf[qt][1], sc[t][qt], 0, 0, 0);
      }

    // ---- p = exp2(score) (raw); lane-local row sums; pack pairs to half2 words ----
    int pk[2][2][2];
#pragma unroll
    for (int t = 0; t < 2; t++)
#pragma unroll
      for (int qt = 0; qt < 2; qt++) {
        float e0 = __builtin_amdgcn_exp2f(sc[t][qt][0]);
        float e1 = __builtin_amdgcn_exp2f(sc[t][qt][1]);
        float e2 = __builtin_amdgcn_exp2f(sc[t][qt][2]);
        float e3 = __builtin_amdgcn_exp2f(sc[t][qt][3]);
        ls[qt] += (e0 + e1) + (e2 + e3);
        pk[t][qt][0] = __builtin_bit_cast(int, __builtin_amdgcn_cvt_pkrtz(e0, e1));
        pk[t][qt][1] = __builtin_bit_cast(int, __builtin_amdgcn_cvt_pkrtz(e2, e3));
      }

    // ---- butterfly (validated r2): tiles (0,1) -> lane holds P[s'_slice=qd*8+jj][q],
    // exactly the PV B-fragment (k=qd*8+jj) for the wave's 32-s' slice.
    half8 pA[2];
#pragma unroll
    for (int qt = 0; qt < 2; qt++) {
      i32x4 fh;
#pragma unroll
      for (int p = 0; p < 2; p++) {
        auto s1 = __builtin_amdgcn_permlane32_swap(pk[0][qt][p], pk[1][qt][p], false, false);
        auto s2 = __builtin_amdgcn_permlane16_swap(s1[0], s1[1], false, false);
        fh[p] = (int)s2[0];      // jj 0..3 slot
        fh[2 + p] = (int)s2[1];  // jj 4..7 slot
      }
      pA[qt] = __builtin_bit_cast(half8, fh);
    }

    // ---- PV: acc[td][qt] += V^T[dk=td*16+m15][s' slice] x P (K=32, one b128 per td) ----
#pragma unroll
    for (int td = 0; td < 4; td++) {
      half8 vf = *(const half8*)(vb + (td * 16 + m15) * 128 + vgr);
#pragma unroll
      for (int qt = 0; qt < 2; qt++)
        acc[td][qt] = __builtin_amdgcn_mfma_f32_16x16x32_f16(vf, pA[qt], acc[td][qt], 0, 0, 0);
    }
    // retire tile it+1's 4 loads, keep tile it+2's 4 in flight (never drain mid-loop)
    if (it < 30) { WAIT_VMCNT(4); } else { WAIT_VMCNT(0); }
    RAW_BARRIER();
    bcur = (bcur == 2) ? 0 : bcur + 1;
    bnxt = (bnxt == 2) ? 0 : bnxt + 1;
  }

  // ---- cross-ws reduction through LDS (K/V buffers dead after final barrier) ----
  float* Ored = (float*)smem;            // [64 q][68] f32 (stride 68: uniform bank spread)
  float* Lred = (float*)(smem + 17408);  // [64 q] f32 (ws=1 partials)

#pragma unroll
  for (int qt = 0; qt < 2; qt++) {  // reduce over quads (disjoint s' per qd)
    ls[qt] += __shfl_xor(ls[qt], 16);
    ls[qt] += __shfl_xor(ls[qt], 32);
  }

  if (ws == 1) {
#pragma unroll
    for (int qt = 0; qt < 2; qt++) {
      int q = wq * 32 + qt * 16 + m15;
      if (qd == 0) Lred[q] = ls[qt];
#pragma unroll
      for (int td = 0; td < 4; td++)
        *(f32x4*)&Ored[q * 68 + td * 16 + qd * 4] = acc[td][qt];
    }
  }
  __syncthreads();

  if (ws == 0) {
#pragma unroll
    for (int qt = 0; qt < 2; qt++) {
      int q = wq * 32 + qt * 16 + m15;
      const float inv = 1.0f / (ls[qt] + Lred[q]);
#pragma unroll
      for (int td = 0; td < 4; td++) {
        f32x4 o = acc[td][qt] + *(const f32x4*)&Ored[q * 68 + td * 16 + qd * 4];
        half4 hv;
#pragma unroll
        for (int r = 0; r < 4; r++) hv[r] = (_Float16)(o[r] * inv);
        *(half4*)(ctx + base + (size_t)(q0 + q) * DMODEL + td * 16 + qd * 4) = hv;
      }
    }
  }
}

// ---------------- output projection v6: 64x64xBK32, 1024 blocks (4/CU), 3-buf counted-vmcnt ----------------
// r10's v5 used __syncthreads with stage-at-top -> drained the same-iteration DMA (the r5
// bug; measured ~87us). v6: counted vmcnt(2) retires tile kt+1 (issued 2 iterations ago),
// tile kt+2 stays in flight across the single raw barrier. 24KB LDS; 16 waves/CU.
__global__ __launch_bounds__(256) void out_gemm(const _Float16* __restrict__ ch,
                                                const _Float16* __restrict__ who,
                                                const float* __restrict__ bo,
                                                float* __restrict__ out) {
  __shared__ __align__(16) _Float16 As[3][64 * 32];  // 4KB x3
  __shared__ __align__(16) _Float16 Bs[3][64 * 32];  // 4KB x3
  const int tid = threadIdx.x;
  const int wave = tid >> 6, lane = tid & 63;
  const int m15 = lane & 15, quad = lane >> 4;
  const int m0 = blockIdx.x * 64, n0 = blockIdx.y * 64;
  const int wm = (wave & 1) * 32, wn = (wave >> 1) * 32;

  // staging: 1 issue each for A,B per tile (256 threads x 16B = 4KB); source pre-swizzled
  const int s_row = tid >> 2;
  const int s_g = (tid & 3) ^ ((s_row >> 1) & 3);  // 64B rows, 4 granules (verified class)
  // read-side swizzled granule byte offset
  const int ra = ((quad ^ ((m15 >> 1) & 3)) << 4);

  f32x4 acc[2][2];
#pragma unroll
  for (int i = 0; i < 2; i++)
#pragma unroll
    for (int j = 0; j < 2; j++) {
      f32x4 z = {0.f, 0.f, 0.f, 0.f};
      acc[i][j] = z;
    }

  const _Float16* asrc = ch + (size_t)(m0 + s_row) * DMODEL + s_g * 8;
  const _Float16* bsrc = who + (size_t)(n0 + s_row) * DMODEL + s_g * 8;

  auto stage = [&](int kk, int nb) {  // 2 vm ops
    async_copy16(asrc + kk, (char*)&As[nb][0] + wave * 1024);
    async_copy16(bsrc + kk, (char*)&Bs[nb][0] + wave * 1024);
  };
  auto compute = [&](int m3) {
    const char* ab = (const char*)&As[m3][0];
    const char* bb = (const char*)&Bs[m3][0];
    half8 af[2], bf[2];
#pragma unroll
    for (int i = 0; i < 2; i++)
      af[i] = *(const half8*)(ab + (wm + i * 16 + m15) * 64 + ra);
#pragma unroll
    for (int j = 0; j < 2; j++)
      bf[j] = *(const half8*)(bb + (wn + j * 16 + m15) * 64 + ra);
#pragma unroll
    for (int i = 0; i < 2; i++)
#pragma unroll
      for (int j = 0; j < 2; j++)
        acc[i][j] = __builtin_amdgcn_mfma_f32_16x16x32_f16(af[i], bf[j], acc[i][j], 0, 0, 0);
  };

  // prologue: tiles 0,1 in flight; retire tile 0 only (tile 1's 2 ops stay outstanding)
  stage(0, 0);
  stage(32, 1);
  WAIT_VMCNT(2);
  RAW_BARRIER();

  int bcur = 0, bnxt = 2;
#pragma unroll 1
  for (int kt = 0; kt < 32; kt++) {
    if (kt < 30) stage((kt + 2) * 32, bnxt);  // dest buf last read at kt-1 (behind barrier)
    compute(bcur);
    if (kt == 31) break;
    if (kt < 30) { WAIT_VMCNT(2); } else { WAIT_VMCNT(0); }
    RAW_BARRIER();
    bcur = (bcur == 2) ? 0 : bcur + 1;
    bnxt = (bnxt == 2) ? 0 : bnxt + 1;
  }

#pragma unroll
  for (int i = 0; i < 2; i++) {
#pragma unroll
    for (int j = 0; j < 2; j++) {
      int gn = n0 + wn + j * 16 + m15;
      float bb = bo[gn];
#pragma unroll
      for (int r = 0; r < 4; r++) {
        int gm = m0 + wm + i * 16 + quad * 4 + r;
        out[(size_t)gm * DMODEL + gn] = acc[i][j][r] + bb;
      }
    }
  }
}

extern "C" void kernel_launch(void* const* d_in, const int* in_sizes, int n_in,
                              void* d_out, int out_size, void* d_ws, size_t ws_size,
                              hipStream_t stream) {
  (void)in_sizes; (void)n_in; (void)out_size; (void)ws_size;
  const float* Q  = (const float*)d_in[0];
  const float* K  = (const float*)d_in[1];
  const float* V  = (const float*)d_in[2];
  const float* wq = (const float*)d_in[3];
  const float* bq = (const float*)d_in[4];
  const float* wk = (const float*)d_in[5];
  const float* bk = (const float*)d_in[6];
  const float* wv = (const float*)d_in[7];
  const float* bv = (const float*)d_in[8];
  const float* wo = (const float*)d_in[9];
  const float* bo = (const float*)d_in[10];
  float* out = (float*)d_out;

  // Scratch plan (16 MB d_ws + d_out reuse), timeline:
  //   qh, kh (fp16, 8 MB each)  -> inside d_out (dead before out_gemm writes fp32 there)
  //   vt (fp16 transposed, 8MB) -> ws[0:8M)   -- alive qkv..attn
  //   wh (fp16 wq|wk|wv, 6 MB)  -> ws[8M:14M) -- alive only during qkv_gemm
  //   ch (fp16 ctx, 8 MB)       -> ws[8M:16M) -- written by attn (overlays wh, disjoint in time)
  //   who (fp16 wo, 2 MB)       -> ws[0:2M)   -- written AFTER attn (overlays dead vt)
  _Float16* qh = (_Float16*)d_out;
  _Float16* kh = qh + (size_t)4194304;
  _Float16* vt = (_Float16*)d_ws;
  _Float16* wh = vt + (size_t)4194304;
  _Float16* ch = vt + (size_t)4194304;
  _Float16* who = (_Float16*)d_ws;

  convert_w<<<dim3(1024, 3), 256, 0, stream>>>(wq, wk, wv, wh);
  qkv_gemm<<<dim3(32, 24), 256, 0, stream>>>(Q, K, V, wh, bq, bk, bv, qh, kh, vt);
  attn_kernel<<<dim3(32, 16, 2), 256, 0, stream>>>(qh, kh, vt, ch);
  convert_wo<<<dim3(1024), 256, 0, stream>>>(wo, who);
  out_gemm<<<dim3(64, 16), 256, 0, stream>>>(ch, who, bo, out);
}

// Round 12
// 221.088 us; speedup vs baseline: 1.1841x; 1.0500x over previous
//
#include <hip/hip_runtime.h>

// Problem constants: B=2, S=2048, D=1024, H=16, DK=64
#define S_LEN 2048
#define DMODEL 1024
#define DHEAD 64

typedef _Float16 half8 __attribute__((ext_vector_type(8)));
typedef _Float16 half4 __attribute__((ext_vector_type(4)));
typedef float f32x4 __attribute__((ext_vector_type(4)));
typedef int i32x4 __attribute__((ext_vector_type(4)));

#define LOG2E 1.4426950408889634f

// async global->LDS, 16B per lane; LDS dest is wave-uniform base, HW writes lane i at base+16*i.
__device__ __forceinline__ void async_copy16(const void* g, void* l) {
  __builtin_amdgcn_global_load_lds((__attribute__((address_space(1))) const void*)g,
                                   (__attribute__((address_space(3))) void*)l,
                                   16, 0, 0);
}

#define WAIT_VMCNT(N) asm volatile("s_waitcnt vmcnt(" #N ")" ::: "memory")
#define WAIT_LGKM0() asm volatile("s_waitcnt lgkmcnt(0)" ::: "memory")
#define RAW_BARRIER() asm volatile("s_barrier" ::: "memory")

// ---------------- convert wq,wk,wv fp32 -> fp16 ----------------
__global__ __launch_bounds__(256) void convert_w(const float* __restrict__ wq,
                                                 const float* __restrict__ wk,
                                                 const float* __restrict__ wv,
                                                 _Float16* __restrict__ dst) {
  const float* src = (blockIdx.y == 0) ? wq : (blockIdx.y == 1) ? wk : wv;
  _Float16* d = dst + (size_t)blockIdx.y * (DMODEL * DMODEL);
  int i = (blockIdx.x * 256 + threadIdx.x) * 4;
  float4 v = *(const float4*)(src + i);
  half4 h;
  h[0] = (_Float16)v.x; h[1] = (_Float16)v.y;
  h[2] = (_Float16)v.z; h[3] = (_Float16)v.w;
  *(half4*)(d + i) = h;
}

// ---------------- convert wo fp32 -> fp16 (runs after attn; vt slot is dead) ----------------
__global__ __launch_bounds__(256) void convert_wo(const float* __restrict__ wo,
                                                  _Float16* __restrict__ dst) {
  int i = (blockIdx.x * 256 + threadIdx.x) * 4;
  float4 v = *(const float4*)(wo + i);
  half4 h;
  h[0] = (_Float16)v.x; h[1] = (_Float16)v.y;
  h[2] = (_Float16)v.z; h[3] = (_Float16)v.w;
  *(half4*)(dst + i) = h;
}

// ---------------- fused QKV projection GEMM v6 (unchanged from r9: best known, ~64us) ----------------
__global__ __launch_bounds__(256, 3) void qkv_gemm(
    const float* __restrict__ Qf, const float* __restrict__ Kf, const float* __restrict__ Vf,
    const _Float16* __restrict__ wh,
    const float* __restrict__ bq, const float* __restrict__ bk, const float* __restrict__ bv,
    _Float16* __restrict__ qo, _Float16* __restrict__ ko, _Float16* __restrict__ vt) {
  __shared__ __align__(16) _Float16 Asb[3][128 * 32];  // 8KB x3
  __shared__ __align__(16) _Float16 Bsb[3][128 * 32];  // 8KB x3
  const int tid = threadIdx.x;
  const int wave = tid >> 6, lane = tid & 63;
  const int m15 = lane & 15, quad = lane >> 4;
  const int m0 = blockIdx.x * 128;
  const int y = blockIdx.y;
  const int sel = (y < 8) ? 2 : (y < 16) ? 0 : 1;  // v first, then q, then k
  const int n0 = (y & 7) * 128;
  const float* Ag = (sel == 0) ? Qf : (sel == 1) ? Kf : Vf;
  const _Float16* Wg = wh + (size_t)sel * (DMODEL * DMODEL);
  const float* bias = (sel == 0) ? bq : (sel == 1) ? bk : bv;

  const int wm = (wave & 1) * 64, wn = (wave >> 1) * 64;

  const int sr = tid >> 1, sc16 = (tid & 1) * 16;
  const int g0 = (tid & 1) * 2, asw = (sr >> 1) & 3;
  const int b_r = lane >> 2, b_g = (lane & 3) ^ ((lane >> 3) & 3);
  const int ra = ((quad ^ ((m15 >> 1) & 3)) << 4);

  f32x4 acc[4][4];
#pragma unroll
  for (int i = 0; i < 4; i++)
#pragma unroll
    for (int j = 0; j < 4; j++) {
      f32x4 z = {0.f, 0.f, 0.f, 0.f};
      acc[i][j] = z;
    }

  const float* ap = Ag + (size_t)(m0 + sr) * DMODEL + sc16;

  auto loadA = [&](int kk, float4 (&s)[4]) {
    const float* p = ap + kk;
    s[0] = ((const float4*)p)[0];
    s[1] = ((const float4*)p)[1];
    s[2] = ((const float4*)p)[2];
    s[3] = ((const float4*)p)[3];
  };
  auto writeA = [&](const float4 (&s)[4], int nb) {
    half8 h0, h1;
    h0[0] = (_Float16)s[0].x; h0[1] = (_Float16)s[0].y; h0[2] = (_Float16)s[0].z; h0[3] = (_Float16)s[0].w;
    h0[4] = (_Float16)s[1].x; h0[5] = (_Float16)s[1].y; h0[6] = (_Float16)s[1].z; h0[7] = (_Float16)s[1].w;
    h1[0] = (_Float16)s[2].x; h1[1] = (_Float16)s[2].y; h1[2] = (_Float16)s[2].z; h1[3] = (_Float16)s[2].w;
    h1[4] = (_Float16)s[3].x; h1[5] = (_Float16)s[3].y; h1[6] = (_Float16)s[3].z; h1[7] = (_Float16)s[3].w;
    char* rb = (char*)&Asb[nb][0] + sr * 64;
    *(half8*)(rb + ((g0 ^ asw) << 4)) = h0;
    *(half8*)(rb + (((g0 + 1) ^ asw) << 4)) = h1;
  };
  auto issueB = [&](int kk, int nb) {
#pragma unroll
    for (int p = 0; p < 2; p++) {
      int row = (p * 4 + wave) * 16 + b_r;
      async_copy16(Wg + (size_t)(n0 + row) * DMODEL + kk + b_g * 8,
                   (char*)&Bsb[nb][0] + p * 4096 + wave * 1024);
    }
  };
  auto compute = [&](int m3) {
    const char* ab = (const char*)&Asb[m3][0];
    const char* bb = (const char*)&Bsb[m3][0];
    half8 af[4], bf[4];
#pragma unroll
    for (int i = 0; i < 4; i++)
      af[i] = *(const half8*)(ab + (wm + i * 16 + m15) * 64 + ra);
#pragma unroll
    for (int j = 0; j < 4; j++)
      bf[j] = *(const half8*)(bb + (wn + j * 16 + m15) * 64 + ra);
#pragma unroll
    for (int i = 0; i < 4; i++)
#pragma unroll
      for (int j = 0; j < 4; j++)
        acc[i][j] = __builtin_amdgcn_mfma_f32_16x16x32_f16(af[i], bf[j], acc[i][j], 0, 0, 0);
  };

  float4 s0[4], s1[4], s2[4];

  issueB(0, 0);
  loadA(0, s0);
  issueB(32, 1);
  loadA(32, s1);
  loadA(64, s2);
  WAIT_VMCNT(10);
  writeA(s0, 0);
  WAIT_LGKM0();
  RAW_BARRIER();

  auto body = [&](int kt, int m3, int bB, int bW, float4 (&ld)[4], const float4 (&wr)[4],
                  int mode) {
    if (mode == 0) {
      issueB((kt + 2) * 32, bB);
      loadA((kt + 3) * 32, ld);
    } else if (mode == 1) {
      issueB((kt + 2) * 32, bB);
    }
    compute(m3);
    if (mode == 3) return;
    if (mode == 0) { WAIT_VMCNT(10); }
    else if (mode == 1) { WAIT_VMCNT(6); }
    else { WAIT_VMCNT(0); }
    writeA(wr, bW);
    WAIT_LGKM0();
    RAW_BARRIER();
  };

#pragma unroll 1
  for (int k3 = 0; k3 < 27; k3 += 3) {
    body(k3 + 0, 0, 2, 1, s0, s1, 0);
    body(k3 + 1, 1, 0, 2, s1, s2, 0);
    body(k3 + 2, 2, 1, 0, s2, s0, 0);
  }
  body(27, 0, 2, 1, s0, s1, 0);
  body(28, 1, 0, 2, s1, s2, 0);
  body(29, 2, 1, 0, s2, s0, 1);
  body(30, 0, 0, 1, s0, s1, 2);
  body(31, 1, 0, 0, s0, s0, 3);

  if (sel != 2) {
    _Float16* outp = (sel == 0) ? qo : ko;
    const float scale = (sel == 0) ? (0.125f * LOG2E) : 1.0f;
#pragma unroll
    for (int i = 0; i < 4; i++) {
#pragma unroll
      for (int j = 0; j < 4; j++) {
        int gn = n0 + wn + j * 16 + m15;
        float bb = bias[gn];
#pragma unroll
        for (int r = 0; r < 4; r++) {
          int gm = m0 + wm + i * 16 + quad * 4 + r;
          outp[(size_t)gm * DMODEL + gn] = (_Float16)((acc[i][j][r] + bb) * scale);
        }
      }
    }
  } else {
#pragma unroll
    for (int i = 0; i < 4; i++) {
      int gm0 = m0 + wm + i * 16 + quad * 4;
      int b = gm0 >> 11, s = gm0 & 2047;
#pragma unroll
      for (int j = 0; j < 4; j++) {
        int gn = n0 + wn + j * 16 + m15;
        int h = gn >> 6, dk = gn & 63;
        float bb = bias[gn];
        half4 hv;
        hv[0] = (_Float16)(acc[i][j][0] + bb);
        hv[1] = (_Float16)(acc[i][j][1] + bb);
        hv[2] = (_Float16)(acc[i][j][2] + bb);
        hv[3] = (_Float16)(acc[i][j][3] + bb);
        *(half4*)(vt + ((size_t)(b * 16 + h) * 64 + dk) * 2048 + s) = hv;
      }
    }
  }
}

// ---------------- flash attention v7: QBLK=128, 8 waves (per-wave code identical to r9 v5) ----------------
// Each 16KB K/V tile now serves 128 q rows (was 64): K/V HBM/L2 traffic halves, DMA issues
// per wave-tile drop 4->2, and per-tile compute doubles (more latency cover for the same
// 2-tile-ahead counted-vmcnt pipeline). Grid (16,16,2)=512 blocks x 8 waves @48KB = 2 blk/CU
// = 16 waves/CU (was 12). Wave (wq=wave>>1 in 0..3, ws=wave&1) owns 32 q x 32 s'.
__global__ __launch_bounds__(512) void attn_kernel(const _Float16* __restrict__ qh,
                                                   const _Float16* __restrict__ kh,
                                                   const _Float16* __restrict__ vt,
                                                   _Float16* __restrict__ ctx) {
  // [0,24K) Ks[3][64][64], [24K,48K) Vs[3][64][64]; epilogue reuses [0,35328) as Ored/Lred.
  __shared__ __align__(16) char smem[49152];
  const int tid = threadIdx.x;
  const int wave = tid >> 6, lane = tid & 63;
  const int m15 = lane & 15, qd = lane >> 4;
  const int wq = wave >> 1, ws = wave & 1;
  const int q0 = blockIdx.x * 128;
  const int h = blockIdx.y, b = blockIdx.z;
  const size_t base = (size_t)b * S_LEN * DMODEL + (size_t)h * DHEAD;  // q/k/ctx base
  const size_t vbase = (size_t)(b * 16 + h) * 64 * 2048;               // vt base

  // Q fragments (pre-scaled by 0.125*log2e): B-layout n=m15 (q row), k=qd*8+j (dk)
  half8 qf[2][2];
#pragma unroll
  for (int qt = 0; qt < 2; qt++) {
    const _Float16* qp = qh + base + (size_t)(q0 + wq * 32 + qt * 16 + m15) * DMODEL + qd * 8;
    qf[qt][0] = *(const half8*)qp;
    qf[qt][1] = *(const half8*)(qp + 32);
  }

  // staging: 8 waves x (1 K + 1 V) issue per tile; per-lane pre-swizzled global sources
  const int l8 = lane >> 3, s8 = lane & 7;
  const int swz = (s8 ^ l8) * 8;  // halfs within a 64-half row
  const _Float16* ksrc = kh + base + (size_t)(wave * 8 + l8) * DMODEL + swz;
  const _Float16* vsrc = vt + vbase + (size_t)(wave * 8 + l8) * S_LEN + swz;

  // read-side swizzled granule byte offsets (row&7 == m15&7 for all read rows)
  const int kgr = ((qd ^ (m15 & 7)) << 4);             // K: dk granule G=qd (dk 0..31)
  const int vgr = (((ws * 4 + qd) ^ (m15 & 7)) << 4);  // V: s' granule G=ws*4+qd
  const int krow = ws * 32 + m15;                      // + 16t

  auto stage = [&](int tile, int bufi) {  // 2 DMA issues: 1 K + 1 V (this wave's 8 rows)
    const int kv = tile * 64;
    async_copy16(ksrc + (size_t)kv * DMODEL, smem + bufi * 8192 + wave * 1024);
    async_copy16(vsrc + kv, smem + 24576 + bufi * 8192 + wave * 1024);
  };

  f32x4 acc[4][2];  // [dk-tile][q-tile] partial O^T over this wave's 32-s' slice
#pragma unroll
  for (int i = 0; i < 4; i++)
#pragma unroll
    for (int j = 0; j < 2; j++) { f32x4 z = {0.f, 0.f, 0.f, 0.f}; acc[i][j] = z; }
  float ls[2] = {0.f, 0.f};  // per-lane partial row sums (q = wq*32 + qt*16 + m15)

  // prologue: tiles 0,1 staged; tile 1's 2 loads stay in flight across the barrier
  stage(0, 0);
  stage(1, 1);
  WAIT_VMCNT(2);  // tile 0 landed
  RAW_BARRIER();

  int bcur = 0, bnxt = 2;  // it%3, (it+2)%3
  for (int it = 0; it < 32; it++) {
    if (it < 30) stage(it + 2, bnxt);  // target buf last read at it-1 (behind barrier)
    const char* kb = smem + bcur * 8192;
    const char* vb = smem + 24576 + bcur * 8192;

    // ---- K slice fragments: A-layout row = ws*32+16t+m15 (s'), k=qd*8+j (dk) ----
    half8 kf[2][2];
#pragma unroll
    for (int t = 0; t < 2; t++) {
      kf[t][0] = *(const half8*)(kb + (krow + 16 * t) * 128 + kgr);
      kf[t][1] = *(const half8*)(kb + (krow + 16 * t) * 128 + (kgr ^ 64));
    }

    // ---- QK^T: sc[t][qt] = P[s'_slice=16t+qd*4+r][q=qt*16+m15] ----
    f32x4 sc[2][2];
#pragma unroll
    for (int t = 0; t < 2; t++)
#pragma unroll
      for (int qt = 0; qt < 2; qt++) {
        f32x4 z = {0.f, 0.f, 0.f, 0.f};
        sc[t][qt] = __builtin_amdgcn_mfma_f32_16x16x32_f16(kf[t][0], qf[qt][0], z, 0, 0, 0);
        sc[t][qt] = __builtin_amdgcn_mfma_f32_16x16x32_f16(kf[t][1], qf[qt][1], sc[t][qt], 0, 0, 0);
      }

    // ---- p = exp2(score) (raw); lane-local row sums; pack pairs to half2 words ----
    int pk[2][2][2];
#pragma unroll
    for (int t = 0; t < 2; t++)
#pragma unroll
      for (int qt = 0; qt < 2; qt++) {
        float e0 = __builtin_amdgcn_exp2f(sc[t][qt][0]);
        float e1 = __builtin_amdgcn_exp2f(sc[t][qt][1]);
        float e2 = __builtin_amdgcn_exp2f(sc[t][qt][2]);
        float e3 = __builtin_amdgcn_exp2f(sc[t][qt][3]);
        ls[qt] += (e0 + e1) + (e2 + e3);
        pk[t][qt][0] = __builtin_bit_cast(int, __builtin_amdgcn_cvt_pkrtz(e0, e1));
        pk[t][qt][1] = __builtin_bit_cast(int, __builtin_amdgcn_cvt_pkrtz(e2, e3));
      }

    // ---- butterfly (validated r2): tiles (0,1) -> lane holds P[s'_slice=qd*8+jj][q],
    // exactly the PV B-fragment (k=qd*8+jj) for the wave's 32-s' slice.
    half8 pA[2];
#pragma unroll
    for (int qt = 0; qt < 2; qt++) {
      i32x4 fh;
#pragma unroll
      for (int p = 0; p < 2; p++) {
        auto s1 = __builtin_amdgcn_permlane32_swap(pk[0][qt][p], pk[1][qt][p], false, false);
        auto s2 = __builtin_amdgcn_permlane16_swap(s1[0], s1[1], false, false);
        fh[p] = (int)s2[0];      // jj 0..3 slot
        fh[2 + p] = (int)s2[1];  // jj 4..7 slot
      }
      pA[qt] = __builtin_bit_cast(half8, fh);
    }

    // ---- PV: acc[td][qt] += V^T[dk=td*16+m15][s' slice] x P (K=32, one b128 per td) ----
#pragma unroll
    for (int td = 0; td < 4; td++) {
      half8 vf = *(const half8*)(vb + (td * 16 + m15) * 128 + vgr);
#pragma unroll
      for (int qt = 0; qt < 2; qt++)
        acc[td][qt] = __builtin_amdgcn_mfma_f32_16x16x32_f16(vf, pA[qt], acc[td][qt], 0, 0, 0);
    }
    // retire tile it+1's 2 loads, keep tile it+2's 2 in flight (never drain mid-loop)
    if (it < 30) { WAIT_VMCNT(2); } else { WAIT_VMCNT(0); }
    RAW_BARRIER();
    bcur = (bcur == 2) ? 0 : bcur + 1;
    bnxt = (bnxt == 2) ? 0 : bnxt + 1;
  }

  // ---- cross-ws reduction through LDS (K/V buffers dead after final barrier) ----
  float* Ored = (float*)smem;            // [128 q][68] f32 (stride 68: uniform bank spread)
  float* Lred = (float*)(smem + 34816);  // [128 q] f32 (ws=1 partials)

#pragma unroll
  for (int qt = 0; qt < 2; qt++) {  // reduce over quads (disjoint s' per qd)
    ls[qt] += __shfl_xor(ls[qt], 16);
    ls[qt] += __shfl_xor(ls[qt], 32);
  }

  if (ws == 1) {
#pragma unroll
    for (int qt = 0; qt < 2; qt++) {
      int q = wq * 32 + qt * 16 + m15;
      if (qd == 0) Lred[q] = ls[qt];
#pragma unroll
      for (int td = 0; td < 4; td++)
        *(f32x4*)&Ored[q * 68 + td * 16 + qd * 4] = acc[td][qt];
    }
  }
  __syncthreads();

  if (ws == 0) {
#pragma unroll
    for (int qt = 0; qt < 2; qt++) {
      int q = wq * 32 + qt * 16 + m15;
      const float inv = 1.0f / (ls[qt] + Lred[q]);
#pragma unroll
      for (int td = 0; td < 4; td++) {
        f32x4 o = acc[td][qt] + *(const f32x4*)&Ored[q * 68 + td * 16 + qd * 4];
        half4 hv;
#pragma unroll
        for (int r = 0; r < 4; r++) hv[r] = (_Float16)(o[r] * inv);
        *(half4*)(ctx + base + (size_t)(q0 + q) * DMODEL + td * 16 + qd * 4) = hv;
      }
    }
  }
}

// ---------------- output projection v6 (unchanged from r11) ----------------
__global__ __launch_bounds__(256) void out_gemm(const _Float16* __restrict__ ch,
                                                const _Float16* __restrict__ who,
                                                const float* __restrict__ bo,
                                                float* __restrict__ out) {
  __shared__ __align__(16) _Float16 As[3][64 * 32];  // 4KB x3
  __shared__ __align__(16) _Float16 Bs[3][64 * 32];  // 4KB x3
  const int tid = threadIdx.x;
  const int wave = tid >> 6, lane = tid & 63;
  const int m15 = lane & 15, quad = lane >> 4;
  const int m0 = blockIdx.x * 64, n0 = blockIdx.y * 64;
  const int wm = (wave & 1) * 32, wn = (wave >> 1) * 32;

  const int s_row = tid >> 2;
  const int s_g = (tid & 3) ^ ((s_row >> 1) & 3);  // 64B rows, 4 granules (verified class)
  const int ra = ((quad ^ ((m15 >> 1) & 3)) << 4);

  f32x4 acc[2][2];
#pragma unroll
  for (int i = 0; i < 2; i++)
#pragma unroll
    for (int j = 0; j < 2; j++) {
      f32x4 z = {0.f, 0.f, 0.f, 0.f};
      acc[i][j] = z;
    }

  const _Float16* asrc = ch + (size_t)(m0 + s_row) * DMODEL + s_g * 8;
  const _Float16* bsrc = who + (size_t)(n0 + s_row) * DMODEL + s_g * 8;

  auto stage = [&](int kk, int nb) {  // 2 vm ops
    async_copy16(asrc + kk, (char*)&As[nb][0] + wave * 1024);
    async_copy16(bsrc + kk, (char*)&Bs[nb][0] + wave * 1024);
  };
  auto compute = [&](int m3) {
    const char* ab = (const char*)&As[m3][0];
    const char* bb = (const char*)&Bs[m3][0];
    half8 af[2], bf[2];
#pragma unroll
    for (int i = 0; i < 2; i++)
      af[i] = *(const half8*)(ab + (wm + i * 16 + m15) * 64 + ra);
#pragma unroll
    for (int j = 0; j < 2; j++)
      bf[j] = *(const half8*)(bb + (wn + j * 16 + m15) * 64 + ra);
#pragma unroll
    for (int i = 0; i < 2; i++)
#pragma unroll
      for (int j = 0; j < 2; j++)
        acc[i][j] = __builtin_amdgcn_mfma_f32_16x16x32_f16(af[i], bf[j], acc[i][j], 0, 0, 0);
  };

  stage(0, 0);
  stage(32, 1);
  WAIT_VMCNT(2);
  RAW_BARRIER();

  int bcur = 0, bnxt = 2;
#pragma unroll 1
  for (int kt = 0; kt < 32; kt++) {
    if (kt < 30) stage((kt + 2) * 32, bnxt);
    compute(bcur);
    if (kt == 31) break;
    if (kt < 30) { WAIT_VMCNT(2); } else { WAIT_VMCNT(0); }
    RAW_BARRIER();
    bcur = (bcur == 2) ? 0 : bcur + 1;
    bnxt = (bnxt == 2) ? 0 : bnxt + 1;
  }

#pragma unroll
  for (int i = 0; i < 2; i++) {
#pragma unroll
    for (int j = 0; j < 2; j++) {
      int gn = n0 + wn + j * 16 + m15;
      float bb = bo[gn];
#pragma unroll
      for (int r = 0; r < 4; r++) {
        int gm = m0 + wm + i * 16 + quad * 4 + r;
        out[(size_t)gm * DMODEL + gn] = acc[i][j][r] + bb;
      }
    }
  }
}

extern "C" void kernel_launch(void* const* d_in, const int* in_sizes, int n_in,
                              void* d_out, int out_size, void* d_ws, size_t ws_size,
                              hipStream_t stream) {
  (void)in_sizes; (void)n_in; (void)out_size; (void)ws_size;
  const float* Q  = (const float*)d_in[0];
  const float* K  = (const float*)d_in[1];
  const float* V  = (const float*)d_in[2];
  const float* wq = (const float*)d_in[3];
  const float* bq = (const float*)d_in[4];
  const float* wk = (const float*)d_in[5];
  const float* bk = (const float*)d_in[6];
  const float* wv = (const float*)d_in[7];
  const float* bv = (const float*)d_in[8];
  const float* wo = (const float*)d_in[9];
  const float* bo = (const float*)d_in[10];
  float* out = (float*)d_out;

  // Scratch plan (16 MB d_ws + d_out reuse), timeline:
  //   qh, kh (fp16, 8 MB each)  -> inside d_out (dead before out_gemm writes fp32 there)
  //   vt (fp16 transposed, 8MB) -> ws[0:8M)   -- alive qkv..attn
  //   wh (fp16 wq|wk|wv, 6 MB)  -> ws[8M:14M) -- alive only during qkv_gemm
  //   ch (fp16 ctx, 8 MB)       -> ws[8M:16M) -- written by attn (overlays wh, disjoint in time)
  //   who (fp16 wo, 2 MB)       -> ws[0:2M)   -- written AFTER attn (overlays dead vt)
  _Float16* qh = (_Float16*)d_out;
  _Float16* kh = qh + (size_t)4194304;
  _Float16* vt = (_Float16*)d_ws;
  _Float16* wh = vt + (size_t)4194304;
  _Float16* ch = vt + (size_t)4194304;
  _Float16* who = (_Float16*)d_ws;

  convert_w<<<dim3(1024, 3), 256, 0, stream>>>(wq, wk, wv, wh);
  qkv_gemm<<<dim3(32, 24), 256, 0, stream>>>(Q, K, V, wh, bq, bk, bv, qh, kh, vt);
  attn_kernel<<<dim3(16, 16, 2), 512, 0, stream>>>(qh, kh, vt, ch);
  convert_wo<<<dim3(1024), 256, 0, stream>>>(wo, who);
  out_gemm<<<dim3(64, 16), 256, 0, stream>>>(ch, who, bo, out);
}